// Round 1
// baseline (2497.577 us; speedup 1.0000x reference)
//
#include <hip/hip_runtime.h>

// MatchLSTM forward (Round 15): ALL phase-A GEMMs now bf16x3 MFMA.
//   R14 validated the pattern (absmax bit-identical, layouts verified).
//   New: mfma_g3_kernel (3-gate GEMM, gather + K=300 tail masking + bias,
//   grid y=24 covers gate row-bases {0,1024,1536}; tile never straddles a
//   gate) + enc_gates elementwise. Encoder preacts reuse pre_m_h as scratch.
// phaseB: Round-10 verbatim (1920 us, VGPR 64, no spills — R12/R13 lesson:
//   1024-thread kernels are pinned at 64 VGPRs; no register double-buffer).
//
// R16: resubmission of R15 verbatim — previous bench was an MI355X broker
//   failure (container failed twice); no counters were captured. Goal of
//   this run: re-establish 2508 us baseline + capture phaseB counters
//   (VALUBusy vs TCC_HIT vs Occupancy) to direct the next edit.

#define DEV static __device__ __forceinline__

DEV float fast_sigmoid(float x) { return 1.0f / (1.0f + __expf(-x)); }
DEV float fast_tanh(float x)    { return 1.0f - 2.0f / (__expf(2.0f * x) + 1.0f); }

DEV unsigned f2bf(float x) {
    unsigned v = __float_as_uint(x);
    return (v + 0x7FFFu + ((v >> 16) & 1u)) >> 16;
}
DEV float blo(unsigned u) { return __uint_as_float(u << 16); }
DEV float bhi(unsigned u) { return __uint_as_float(u & 0xFFFF0000u); }

DEV float ntload(const float* p) { return __builtin_nontemporal_load(p); }

typedef __attribute__((ext_vector_type(8))) short bfrag;   // 8 bf16
typedef __attribute__((ext_vector_type(4))) float ffrag;   // 4 fp32 acc

DEV void cvt_hilo(const float* v, bfrag& hi, bfrag& lo)
{
#pragma unroll
    for (int z = 0; z < 8; ++z) {
        unsigned h = f2bf(v[z]);
        hi[z] = (short)h;
        lo[z] = (short)f2bf(v[z] - __uint_as_float(h << 16));
    }
}

// ---------------------------------------------------------------------------
// MFMA GEMM (validated R14): C[M][512] = A[M][512] . W[512][512]^T, bf16x3.
// Block 256 thr / 4 waves; WG tile 64M x 64N; wave = 16M x 64N.
// ---------------------------------------------------------------------------
__global__ __launch_bounds__(256) void mfma_nt_kernel(
    const float* __restrict__ A, const float* __restrict__ W,
    float* __restrict__ C)
{
    const int wv   = threadIdx.x >> 6;
    const int lane = threadIdx.x & 63;
    const int row  = lane & 15;
    const int quad = lane >> 4;
    const int m0 = blockIdx.x * 64 + wv * 16;
    const int n0 = blockIdx.y * 64;

    ffrag acc[4];
#pragma unroll
    for (int n = 0; n < 4; ++n)
#pragma unroll
        for (int r = 0; r < 4; ++r) acc[n][r] = 0.0f;

    for (int k0 = 0; k0 < 512; k0 += 32) {
        const float* ap = A + (size_t)(m0 + row) * 512 + k0 + quad * 8;
        float4 aA = *(const float4*)ap;
        float4 aB = *(const float4*)(ap + 4);
        float av[8] = {aA.x, aA.y, aA.z, aA.w, aB.x, aB.y, aB.z, aB.w};
        bfrag ahi, alo;
        cvt_hilo(av, ahi, alo);
#pragma unroll
        for (int n = 0; n < 4; ++n) {
            const float* wp = W + (size_t)(n0 + n * 16 + row) * 512 + k0 + quad * 8;
            float4 wA = *(const float4*)wp;
            float4 wB = *(const float4*)(wp + 4);
            float wvv[8] = {wA.x, wA.y, wA.z, wA.w, wB.x, wB.y, wB.z, wB.w};
            bfrag whi, wlo;
            cvt_hilo(wvv, whi, wlo);
            acc[n] = __builtin_amdgcn_mfma_f32_16x16x32_bf16(ahi, whi, acc[n], 0, 0, 0);
            acc[n] = __builtin_amdgcn_mfma_f32_16x16x32_bf16(alo, whi, acc[n], 0, 0, 0);
            acc[n] = __builtin_amdgcn_mfma_f32_16x16x32_bf16(ahi, wlo, acc[n], 0, 0, 0);
        }
    }
#pragma unroll
    for (int n = 0; n < 4; ++n)
#pragma unroll
        for (int r = 0; r < 4; ++r)
            C[(size_t)(m0 + quad * 4 + r) * 512 + n0 + n * 16 + row] = acc[n][r];
}

// ---------------------------------------------------------------------------
// 3-gate MFMA GEMM: P[(m*3+g)*512+j] = A[m,:] . W[grow(g)+j,:] + b1 + b2.
// grid = (M/64, 24): blockIdx.y>>3 = gate (block-uniform), (y&7)*64 = j-tile.
// GATHER: A row through gidx. K-tail (K=300): guarded scalar loads on the
// final K-step only (no OOB read past embed's last row).
// ---------------------------------------------------------------------------
template<int GATHER>
__global__ __launch_bounds__(256) void mfma_g3_kernel(
    const float* __restrict__ A, const int* __restrict__ gidx,
    int lda, int K,
    const float* __restrict__ W, int ldw,
    const float* __restrict__ bias1, const float* __restrict__ bias2,
    float* __restrict__ out)
{
    const int wv   = threadIdx.x >> 6;
    const int lane = threadIdx.x & 63;
    const int row  = lane & 15;
    const int quad = lane >> 4;
    const int m0   = blockIdx.x * 64 + wv * 16;
    const int gate = blockIdx.y >> 3;
    const int gbase = (gate == 0) ? 0 : (gate == 1 ? 1024 : 1536);
    const int j0   = (blockIdx.y & 7) * 64;

    const int arow = GATHER ? gidx[m0 + row] : (m0 + row);

    ffrag acc[4];
#pragma unroll
    for (int n = 0; n < 4; ++n)
#pragma unroll
        for (int r = 0; r < 4; ++r) acc[n][r] = 0.0f;

    for (int k0 = 0; k0 < K; k0 += 32) {
        const bool tail = (k0 + 32 > K);
        float av[8];
        if (!tail) {
            const float* ap = A + (size_t)arow * lda + k0 + quad * 8;
            float4 aA = *(const float4*)ap;
            float4 aB = *(const float4*)(ap + 4);
            av[0]=aA.x; av[1]=aA.y; av[2]=aA.z; av[3]=aA.w;
            av[4]=aB.x; av[5]=aB.y; av[6]=aB.z; av[7]=aB.w;
        } else {
#pragma unroll
            for (int z = 0; z < 8; ++z) {
                int kk = k0 + quad * 8 + z;
                av[z] = (kk < K) ? A[(size_t)arow * lda + kk] : 0.0f;
            }
        }
        bfrag ahi, alo;
        cvt_hilo(av, ahi, alo);
#pragma unroll
        for (int n = 0; n < 4; ++n) {
            const int wrow = gbase + j0 + n * 16 + row;
            float wvv[8];
            if (!tail) {
                const float* wp = W + (size_t)wrow * ldw + k0 + quad * 8;
                float4 wA = *(const float4*)wp;
                float4 wB = *(const float4*)(wp + 4);
                wvv[0]=wA.x; wvv[1]=wA.y; wvv[2]=wA.z; wvv[3]=wA.w;
                wvv[4]=wB.x; wvv[5]=wB.y; wvv[6]=wB.z; wvv[7]=wB.w;
            } else {
#pragma unroll
                for (int z = 0; z < 8; ++z) {
                    int kk = k0 + quad * 8 + z;
                    wvv[z] = (kk < K) ? W[(size_t)wrow * ldw + kk] : 0.0f;
                }
            }
            bfrag whi, wlo;
            cvt_hilo(wvv, whi, wlo);
            acc[n] = __builtin_amdgcn_mfma_f32_16x16x32_bf16(ahi, whi, acc[n], 0, 0, 0);
            acc[n] = __builtin_amdgcn_mfma_f32_16x16x32_bf16(alo, whi, acc[n], 0, 0, 0);
            acc[n] = __builtin_amdgcn_mfma_f32_16x16x32_bf16(ahi, wlo, acc[n], 0, 0, 0);
        }
    }
#pragma unroll
    for (int n = 0; n < 4; ++n) {
        const int j = j0 + n * 16 + row;
        const float bb = bias1[gbase + j] + bias2[gbase + j];
#pragma unroll
        for (int r = 0; r < 4; ++r) {
            const int m = m0 + quad * 4 + r;
            out[((size_t)m * 3 + gate) * 512 + j] = acc[n][r] + bb;
        }
    }
}

// ---------------------------------------------------------------------------
// Encoder gate math: h[m][j] = sig(o)*tanh(sig(i)*tanh(g)), preacts in
// P[(m*3+g)*512+j] (biases already added). 4M elems, float4.
// ---------------------------------------------------------------------------
__global__ __launch_bounds__(256) void enc_gates_kernel(
    const float* __restrict__ P, float* __restrict__ h)
{
    const int i = blockIdx.x * 256 + threadIdx.x;     // 0 .. 1,048,575
    const int m = i >> 7;
    const int j4 = (i & 127) * 4;
    const float* p = P + (size_t)m * 1536 + j4;
    float4 gi = *(const float4*)p;
    float4 gg = *(const float4*)(p + 512);
    float4 go = *(const float4*)(p + 1024);
    float4 r;
    r.x = fast_sigmoid(go.x) * fast_tanh(fast_sigmoid(gi.x) * fast_tanh(gg.x));
    r.y = fast_sigmoid(go.y) * fast_tanh(fast_sigmoid(gi.y) * fast_tanh(gg.y));
    r.z = fast_sigmoid(go.z) * fast_tanh(fast_sigmoid(gi.z) * fast_tanh(gg.z));
    r.w = fast_sigmoid(go.w) * fast_tanh(fast_sigmoid(gi.w) * fast_tanh(gg.w));
    *(float4*)&h[(size_t)m * 512 + j4] = r;
}

// ---------------------------------------------------------------------------
// Transpose + bf16-pack into uint4 layout (verified, absmax 9.8e-4).
// ---------------------------------------------------------------------------
__global__ __launch_bounds__(256) void trans_pack_kernel(
    const float* __restrict__ W, int ld, int gates,
    unsigned* __restrict__ out, int out_ld)
{
    __shared__ float tile[64][129];
    const int j0 = blockIdx.x * 64;
    const int h0 = blockIdx.y * 128;
    const int g  = blockIdx.z;
    const int row_base = gates ? (g == 0 ? 0 : (g == 1 ? 1024 : 1536)) : 0;
    const int out_col  = gates ? g * 512 : 0;

    for (int i = threadIdx.x; i < 64 * 128; i += 256) {
        int jj = i >> 7, hh = i & 127;
        tile[jj][hh] = W[(size_t)(row_base + j0 + jj) * ld + h0 + hh];
    }
    __syncthreads();
    for (int i = threadIdx.x; i < 4096; i += 256) {
        int jj = i & 63, q = i >> 6;
        int gq = h0 / 2 + q;
        unsigned lo = f2bf(tile[jj][2 * q]);
        unsigned hi = f2bf(tile[jj][2 * q + 1]);
        int col = out_col + j0 + jj;
        out[(size_t)(gq >> 2) * (4 * out_ld) + 4 * col + (gq & 3)] = lo | (hi << 16);
    }
}

// ---------------------------------------------------------------------------
// Phase B: Round-10 kernel VERBATIM (1920 us, VGPR 64, no spills).
// ---------------------------------------------------------------------------
__global__ __launch_bounds__(1024) void phaseB_kernel(
    const float* __restrict__ pre_s, const float* __restrict__ pre_t,
    const float* __restrict__ h_s,   const float* __restrict__ pre_m_h,
    const unsigned* __restrict__ WmT2, const unsigned* __restrict__ W3t2,
    const float* __restrict__ w_e,
    const float* __restrict__ fc_w,  const float* __restrict__ fc_b,
    float* __restrict__ out)
{
    __shared__ __align__(16) float hm[512];
    __shared__ __align__(16) float av[512];
    __shared__ __align__(16) float base[512];
    __shared__ __align__(16) float wesh[512];
    __shared__ __align__(16) float sc[64];
    __shared__ __align__(16) float red[2 * 512];
    __shared__ __align__(16) float red3[3 * 2 * 512];

    const int b    = blockIdx.x;
    const int tid  = threadIdx.x;
    const int wv   = tid >> 6;
    const int lane = tid & 63;
    const int j    = tid & 511;
    const int kh   = tid >> 9;
    const int hq0  = kh * 32;

    if (tid < 512) { wesh[tid] = w_e[tid]; hm[tid] = 0.0f; }
    __syncthreads();

    const uint4* wpm = (const uint4*)WmT2 + j;
    const uint4* wp3 = (const uint4*)W3t2 + j;

    for (int k = 0; k < 64; ++k) {
        if (k > 0) {
            float p = 0.0f;
#pragma unroll 1
            for (int c0 = 0; c0 < 32; c0 += 8) {
                uint4 u[8];
#pragma unroll
                for (int z = 0; z < 8; ++z) u[z] = wpm[(size_t)(hq0 + c0 + z) * 512];
#pragma unroll
                for (int z = 0; z < 8; ++z) {
                    const float* hv = &hm[(hq0 + c0 + z) * 8];
                    float4 vA = *(const float4*)hv;
                    float4 vB = *(const float4*)(hv + 4);
                    p += blo(u[z].x) * vA.x + bhi(u[z].x) * vA.y
                       + blo(u[z].y) * vA.z + bhi(u[z].y) * vA.w
                       + blo(u[z].z) * vB.x + bhi(u[z].z) * vB.y
                       + blo(u[z].w) * vB.z + bhi(u[z].w) * vB.w;
                }
            }
            red[kh * 512 + j] = p;
        }
        __syncthreads();
        if (tid < 512) {
            float wmj = (k > 0) ? (red[tid] + red[512 + tid]) : 0.0f;
            base[tid] = ntload(&pre_t[((size_t)k * 128 + b) * 512 + tid]) + wmj;
        }
        __syncthreads();

#pragma unroll
        for (int tt = 0; tt < 4; ++tt) {
            int t = wv * 4 + tt;
            const float* ps = pre_s + ((size_t)t * 128 + b) * 512;
            float p = 0.0f;
#pragma unroll
            for (int u = 0; u < 8; ++u) {
                int h = lane + 64 * u;
                p += wesh[h] * fast_tanh(ntload(&ps[h]) + base[h]);
            }
#pragma unroll
            for (int off = 32; off; off >>= 1) p += __shfl_xor(p, off);
            if (lane == 0) sc[t] = p;
        }
        __syncthreads();
        if (wv == 0) {
            float s = sc[lane], mx = s;
#pragma unroll
            for (int off = 32; off; off >>= 1) mx = fmaxf(mx, __shfl_xor(mx, off));
            float e = __expf(s - mx), sum = e;
#pragma unroll
            for (int off = 32; off; off >>= 1) sum += __shfl_xor(sum, off);
            sc[lane] = e / sum;
        }
        __syncthreads();

        {
            const float* hp = h_s + (size_t)b * 512 + j;
            float p = 0.0f;
#pragma unroll
            for (int t4 = 0; t4 < 8; ++t4) {
                int t = kh * 32 + t4 * 4;
                float4 s4 = *(const float4*)&sc[t];
                p += s4.x * ntload(&hp[(size_t)(t + 0) * 65536])
                   + s4.y * ntload(&hp[(size_t)(t + 1) * 65536])
                   + s4.z * ntload(&hp[(size_t)(t + 2) * 65536])
                   + s4.w * ntload(&hp[(size_t)(t + 3) * 65536]);
            }
            red[kh * 512 + j] = p;
        }
        __syncthreads();
        if (tid < 512) av[tid] = red[tid] + red[512 + tid];
        __syncthreads();

#pragma unroll 1
        for (int g = 0; g < 3; ++g) {
            const uint4* wg = wp3 + g * 512;
            float p = 0.0f;
#pragma unroll 1
            for (int c0 = 0; c0 < 32; c0 += 8) {
                uint4 u[8];
#pragma unroll
                for (int z = 0; z < 8; ++z) u[z] = wg[(size_t)(hq0 + c0 + z) * 1536];
#pragma unroll
                for (int z = 0; z < 8; ++z) {
                    const float* vv = &av[(hq0 + c0 + z) * 8];
                    float4 vA = *(const float4*)vv;
                    float4 vB = *(const float4*)(vv + 4);
                    p += blo(u[z].x) * vA.x + bhi(u[z].x) * vA.y
                       + blo(u[z].y) * vA.z + bhi(u[z].y) * vA.w
                       + blo(u[z].z) * vB.x + bhi(u[z].z) * vB.y
                       + blo(u[z].w) * vB.z + bhi(u[z].w) * vB.w;
                }
            }
            red3[(g * 2 + kh) * 512 + j] = p;
        }
        __syncthreads();
        if (tid < 512) {
            const size_t m = (size_t)k * 128 + b;
            float gi = red3[tid]        + red3[512 + tid]
                     + ntload(&pre_m_h[(m * 3 + 0) * 512 + tid]);
            float gg = red3[1024 + tid] + red3[1536 + tid]
                     + ntload(&pre_m_h[(m * 3 + 1) * 512 + tid]);
            float go = red3[2048 + tid] + red3[2560 + tid]
                     + ntload(&pre_m_h[(m * 3 + 2) * 512 + tid]);
            float cc = fast_sigmoid(gi) * fast_tanh(gg);
            hm[tid]  = fast_sigmoid(go) * fast_tanh(cc);
        }
        __syncthreads();
    }

    if (wv < 3) {
        float p = 0.0f;
#pragma unroll
        for (int u = 0; u < 8; ++u) {
            int h = lane + 64 * u;
            p += hm[h] * fc_w[wv * 512 + h];
        }
#pragma unroll
        for (int off = 32; off; off >>= 1) p += __shfl_xor(p, off);
        if (lane == 0) out[b * 3 + wv] = p + fc_b[wv];
    }
}

extern "C" void kernel_launch(void* const* d_in, const int* in_sizes, int n_in,
                              void* d_out, int out_size, void* d_ws, size_t ws_size,
                              hipStream_t stream)
{
    (void)in_sizes; (void)n_in; (void)out_size;
    const int*   premise    = (const int*)d_in[0];
    const int*   hypothesis = (const int*)d_in[2];
    const float* embed  = (const float*)d_in[4];
    const float* w_e    = (const float*)d_in[5];
    const float* Ws     = (const float*)d_in[6];
    const float* Wt     = (const float*)d_in[7];
    const float* Wm     = (const float*)d_in[8];
    const float* Wih_p  = (const float*)d_in[9];
    const float* bih_p  = (const float*)d_in[10];
    const float* bhh_p  = (const float*)d_in[11];
    const float* Wih_h  = (const float*)d_in[12];
    const float* bih_h  = (const float*)d_in[13];
    const float* bhh_h  = (const float*)d_in[14];
    const float* Wih_m  = (const float*)d_in[15];
    const float* bih_m  = (const float*)d_in[16];
    const float* bhh_m  = (const float*)d_in[17];
    const float* fc_w   = (const float*)d_in[18];
    const float* fc_b   = (const float*)d_in[19];

    float* ws      = (float*)d_ws;
    float* h_s     = ws;                      // 8192*512
    float* h_t     = h_s    + 4194304;        // 8192*512 (aliased by packs)
    float* pre_s   = h_t    + 4194304;
    float* pre_t   = pre_s  + 4194304;
    float* pre_m_h = pre_t  + 4194304;        // 8192*3*512 (+ encoder scratch)
    unsigned* WmT2 = (unsigned*)h_t;          // aliases h_t after last reader
    unsigned* W3t2 = WmT2 + 131072;
    float* outp    = (float*)d_out;
    if (ws_size < (size_t)29556736 * 4) return;

    dim3 blk(256);
    float* P = pre_m_h;                       // encoder preact scratch

    // Phase A (all MFMA)
    mfma_g3_kernel<1><<<dim3(128, 24), blk, 0, stream>>>(
        embed, premise, 300, 300, Wih_p, 300, bih_p, bhh_p, P);
    enc_gates_kernel<<<4096, blk, 0, stream>>>(P, h_s);
    mfma_g3_kernel<1><<<dim3(128, 24), blk, 0, stream>>>(
        embed, hypothesis, 300, 300, Wih_h, 300, bih_h, bhh_h, P);
    enc_gates_kernel<<<4096, blk, 0, stream>>>(P, h_t);
    mfma_nt_kernel<<<dim3(128, 8), blk, 0, stream>>>(h_s, Ws, pre_s);
    mfma_nt_kernel<<<dim3(128, 8), blk, 0, stream>>>(h_t, Wt, pre_t);
    mfma_g3_kernel<0><<<dim3(128, 24), blk, 0, stream>>>(
        h_t, nullptr, 512, 512, Wih_m + 512, 1024, bih_m, bhh_m, pre_m_h);

    // Weight transposes (after h_t's last reader; outputs alias h_t space)
    trans_pack_kernel<<<dim3(8, 4, 1), blk, 0, stream>>>(Wm, 512, 0, WmT2, 512);
    trans_pack_kernel<<<dim3(8, 4, 3), blk, 0, stream>>>(Wih_m, 1024, 1, W3t2, 1536);

    // Phase B (Round-10 verbatim)
    phaseB_kernel<<<dim3(128), dim3(1024), 0, stream>>>(
        pre_s, pre_t, h_s, pre_m_h, WmT2, W3t2, w_e, fc_w, fc_b, outp);
}